// Round 7
// baseline (7567.255 us; speedup 1.0000x reference)
//
#include <hip/hip_runtime.h>
#include <stdint.h>

#define BB 64
#define TT 512
#define EE 512
#define HH 1024
#define GG 4096

#define NSG 64          // WGs per stage
#define XP0_SLOTS 8
#define H0_SLOTS 8
#define XP1_SLOTS 4
#define H1_SLOTS 4
#define CPAD 16         // u32 stride per counter (64 B line padding)

typedef short v8b __attribute__((ext_vector_type(8)));
typedef float v4f __attribute__((ext_vector_type(4)));
typedef unsigned short u16;
typedef unsigned int u32;
typedef unsigned long long u64;

__device__ __forceinline__ u16 f2bf(float f) {
  union { float f; u32 i; } v; v.f = f;
  u32 u = v.i;
  return (u16)((u + 0x7FFFu + ((u >> 16) & 1u)) >> 16);
}
__device__ __forceinline__ float sigm(float x) { return 1.0f / (1.0f + __expf(-x)); }

// ---- MALL-coherent accessors, ALL compiler-visible (auto waitcnt), agent scope ----
__device__ __forceinline__ v8b ldb16a(const u16* p) {
  union { v8b b; u64 q[2]; } u;
  u.q[0] = __hip_atomic_load((const u64*)p,     __ATOMIC_RELAXED, __HIP_MEMORY_SCOPE_AGENT);
  u.q[1] = __hip_atomic_load((const u64*)p + 1, __ATOMIC_RELAXED, __HIP_MEMORY_SCOPE_AGENT);
  return u.b;
}
__device__ __forceinline__ v4f ldf16a(const float* p) {
  union { v4f f; u64 q[2]; } u;
  u.q[0] = __hip_atomic_load((const u64*)p,     __ATOMIC_RELAXED, __HIP_MEMORY_SCOPE_AGENT);
  u.q[1] = __hip_atomic_load((const u64*)p + 1, __ATOMIC_RELAXED, __HIP_MEMORY_SCOPE_AGENT);
  return u.f;
}
__device__ __forceinline__ void stg16_f(float* p, v4f v) {
  union { v4f f; u64 q[2]; } u; u.f = v;
  __hip_atomic_store((u64*)p,     u.q[0], __ATOMIC_RELAXED, __HIP_MEMORY_SCOPE_AGENT);
  __hip_atomic_store((u64*)p + 1, u.q[1], __ATOMIC_RELAXED, __HIP_MEMORY_SCOPE_AGENT);
}
__device__ __forceinline__ void stg2_h(u16* p, u16 v) {
  __hip_atomic_store(p, v, __ATOMIC_RELAXED, __HIP_MEMORY_SCOPE_AGENT);
}
__device__ __forceinline__ void stg4_f(float* p, float v) {
  __hip_atomic_store(p, v, __ATOMIC_RELAXED, __HIP_MEMORY_SCOPE_AGENT);
}
__device__ __forceinline__ void drain_stores() {
  asm volatile("s_waitcnt vmcnt(0)" ::: "memory");
}
__device__ __forceinline__ void compiler_barrier() {
  asm volatile("" ::: "memory");
}

// ---------------- prep: gather embeddings (fp32->bf16), zero counters + h rings, lens --------
__global__ void prep_kernel(const int* __restrict__ x, const float* __restrict__ emb,
                            u16* __restrict__ e16, u16* __restrict__ h0r, u16* __restrict__ h1r,
                            int* __restrict__ lens, u32* cnts, int cnt_u32s) {
  long stride = (long)gridDim.x * blockDim.x;
  long gid = (long)blockIdx.x * blockDim.x + threadIdx.x;
  const long totalE = (long)BB * TT * EE;
  for (long i = gid; i < totalE; i += stride) {
    int d = (int)(i % EE);
    long bt = i / EE;
    int tok = x[bt];
    e16[i] = f2bf(emb[(long)tok * EE + d]);
  }
  for (long i = gid; i < (long)cnt_u32s; i += stride) cnts[i] = 0u;
  const long ring0 = (long)H0_SLOTS * BB * HH;
  for (long i = gid; i < ring0; i += stride) h0r[i] = 0;
  const long ring1 = (long)H1_SLOTS * BB * HH;
  for (long i = gid; i < ring1; i += stride) h1r[i] = 0;
  int gwave = (int)(gid >> 6);
  int lane = (int)(gid & 63);
  if (gwave < BB) {
    int cnt = 0;
    for (int t2 = lane; t2 < TT; t2 += 64) cnt += (x[gwave * TT + t2] == 0) ? 1 : 0;
    for (int off = 32; off; off >>= 1) cnt += __shfl_down(cnt, off, 64);
    if (lane == 0) lens[gwave] = TT - cnt;
  }
}

// ---------------- sync: per-(stage, round) aggregate counters, 64 B padded ----------------
__device__ __forceinline__ void spin64(const u32* c) {
  while (__hip_atomic_load(c, __ATOMIC_RELAXED, __HIP_MEMORY_SCOPE_AGENT) < (u32)NSG)
    __builtin_amdgcn_s_sleep(16);
}
__device__ __forceinline__ void bump(u32* c) {
  if (threadIdx.x == 0)
    __hip_atomic_fetch_add(c, 1u, __ATOMIC_RELAXED, __HIP_MEMORY_SCOPE_AGENT);
}

extern __shared__ short Wlds[];  // dynamic, 128 KB

// one 32-wide K-block: 4 ds_read_b128 (4 n-tiles of 16 rows) + 4 MFMA
#define KQUAD(FR, PK) \
  { const short* wb = &Wlds[(((PK) * 4 + q) * 64 + m16) * 8]; \
    v8b w0 = *(const v8b*)(wb); \
    v8b w1 = *(const v8b*)(wb + 128); \
    v8b w2 = *(const v8b*)(wb + 256); \
    v8b w3 = *(const v8b*)(wb + 384); \
    a0 = __builtin_amdgcn_mfma_f32_16x16x32_bf16(FR, w0, a0, 0, 0, 0); \
    a1 = __builtin_amdgcn_mfma_f32_16x16x32_bf16(FR, w1, a1, 0, 0, 0); \
    a2 = __builtin_amdgcn_mfma_f32_16x16x32_bf16(FR, w2, a2, 0, 0, 0); \
    a3 = __builtin_amdgcn_mfma_f32_16x16x32_bf16(FR, w3, a3, 0, 0, 0); }

// K=1024 MALL-coherent h read + MFMA: 16+16 buffers issued up-front (~1 latency epoch)
__device__ __forceinline__ void khloop(const u16* hp, int q, int m16,
                                       v4f& a0, v4f& a1, v4f& a2, v4f& a3) {
  v8b A[16], B[16];
#pragma unroll
  for (int i = 0; i < 16; ++i) A[i] = ldb16a(hp + i * 32);
#pragma unroll
  for (int i = 0; i < 16; ++i) B[i] = ldb16a(hp + (16 + i) * 32);
#pragma unroll
  for (int i = 0; i < 16; ++i) KQUAD(A[i], i);
#pragma unroll
  for (int i = 0; i < 16; ++i) KQUAD(B[i], 16 + i);
}

// ---------------- persistent pipeline kernel: 4 stages x 64 WGs, 1 WG/CU ----------------
__global__ __launch_bounds__(256, 1) void lstm_persist(
    const u16* __restrict__ e16,
    const float* __restrict__ Wih0, const float* __restrict__ Whh0, const float* __restrict__ b0,
    const float* __restrict__ Wih1, const float* __restrict__ Whh1, const float* __restrict__ b1,
    const int* __restrict__ lens,
    float* __restrict__ xp0, float* __restrict__ xp1,
    u16* __restrict__ h0r, u16* __restrict__ h1r,
    float* __restrict__ lasth,
    u32* cA0, u32* cL0, u32* cA1, u32* cL1) {
  const int wg = blockIdx.x;
  const int tid = threadIdx.x;
  const int wave = tid >> 6;
  const int lane = tid & 63;
  const int m16 = lane & 15;
  const int q = lane >> 4;
  const int bm = wave * 16 + m16;    // A-frag batch row (M)
  const int bq = wave * 16 + q * 4;  // C-tile batch base (row = q*4+reg)
  const int stage = wg >> 6;
  const int sid = wg & 63;

  if (stage == 0) {
    // ===== A0: xp0[t] = W_ih0 @ e_t + b0 (rows sid*64..+63, K=512) =====
    const int rbase = sid * 64;
    for (int c2 = tid; c2 < 64 * 64; c2 += 256) {
      int r = c2 >> 6, kb = c2 & 63;
      const float* src = Wih0 + (long)(rbase + r) * EE + kb * 8;
      v8b w;
#pragma unroll
      for (int j = 0; j < 8; ++j) w[j] = (short)f2bf(src[j]);
      *(v8b*)&Wlds[(kb * 64 + r) * 8] = w;
    }
    __syncthreads();
    float bias[4];
#pragma unroll
    for (int nt = 0; nt < 4; ++nt) bias[nt] = b0[rbase + nt * 16 + m16];
    for (int t = 0; t < TT; ++t) {
      if (tid == 0 && t >= XP0_SLOTS) spin64(&cL0[(t - XP0_SLOTS) * CPAD]);
      __syncthreads();
      compiler_barrier();
      v4f a0 = {0,0,0,0}, a1 = {0,0,0,0}, a2 = {0,0,0,0}, a3 = {0,0,0,0};
      const u16* ap = e16 + (long)bm * (TT * EE) + (long)t * EE + q * 8;
#pragma unroll
      for (int kb = 0; kb < 16; ++kb) {
        v8b fr = *(const v8b*)(ap + kb * 32);  // plain cached load (e16 static)
        KQUAD(fr, kb);
      }
      float* xpS = xp0 + (long)(t & (XP0_SLOTS - 1)) * (GG * BB);
      stg16_f(&xpS[(long)(rbase + 0 * 16 + m16) * BB + bq], a0 + bias[0]);
      stg16_f(&xpS[(long)(rbase + 1 * 16 + m16) * BB + bq], a1 + bias[1]);
      stg16_f(&xpS[(long)(rbase + 2 * 16 + m16) * BB + bq], a2 + bias[2]);
      stg16_f(&xpS[(long)(rbase + 3 * 16 + m16) * BB + bq], a3 + bias[3]);
      drain_stores();
      __syncthreads();
      bump(&cA0[t * CPAD]);
    }
  } else if (stage == 1) {
    // ===== L0: gates = xp0 + W_hh0 @ h0[t-1]; 16 units, lane-local cell =====
    const int ubase = sid * 16;
    for (int c2 = tid; c2 < 64 * 128; c2 += 256) {
      int r = c2 >> 7, kb = c2 & 127;
      int grow = (r >> 4) * HH + ubase + (r & 15);  // rows: [i 0..15 | f | g | o]
      const float* src = Whh0 + (long)grow * HH + kb * 8;
      v8b w;
#pragma unroll
      for (int j = 0; j < 8; ++j) w[j] = (short)f2bf(src[j]);
      *(v8b*)&Wlds[(kb * 64 + r) * 8] = w;
    }
    __syncthreads();
    float cst[4] = {0.f, 0.f, 0.f, 0.f};
    for (int t = 0; t < TT; ++t) {
      if (tid == 0) spin64(&cA0[t * CPAD]);
      else if (tid == 64 && t >= 1) spin64(&cL0[(t - 1) * CPAD]);
      else if (tid == 128 && t >= H0_SLOTS) spin64(&cA1[(t - H0_SLOTS) * CPAD]);
      __syncthreads();
      compiler_barrier();
      const float* xpS = xp0 + (long)(t & (XP0_SLOTS - 1)) * (GG * BB);
      v4f xq0 = ldf16a(&xpS[(long)(0 * HH + ubase + m16) * BB + bq]);
      v4f xq1 = ldf16a(&xpS[(long)(1 * HH + ubase + m16) * BB + bq]);
      v4f xq2 = ldf16a(&xpS[(long)(2 * HH + ubase + m16) * BB + bq]);
      v4f xq3 = ldf16a(&xpS[(long)(3 * HH + ubase + m16) * BB + bq]);
      v4f a0 = {0,0,0,0}, a1 = {0,0,0,0}, a2 = {0,0,0,0}, a3 = {0,0,0,0};
      const u16* hp = h0r + ((t + H0_SLOTS - 1) & (H0_SLOTS - 1)) * (BB * HH) + bm * HH + q * 8;
      khloop(hp, q, m16, a0, a1, a2, a3);
      a0 += xq0; a1 += xq1; a2 += xq2; a3 += xq3;   // i, f, g, o
      u16* hw = h0r + (t & (H0_SLOTS - 1)) * (BB * HH);
#pragma unroll
      for (int r = 0; r < 4; ++r) {
        float cn = sigm(a1[r]) * cst[r] + sigm(a0[r]) * tanhf(a2[r]);
        cst[r] = cn;
        float hv = sigm(a3[r]) * tanhf(cn);
        stg2_h(&hw[(bq + r) * HH + ubase + m16], f2bf(hv));
      }
      drain_stores();
      __syncthreads();
      bump(&cL0[t * CPAD]);
    }
  } else if (stage == 2) {
    // ===== A1: xp1[t] = W_ih1 @ h0[t] + b1 (rows sid*64..+63, K=1024) =====
    const int rbase = sid * 64;
    for (int c2 = tid; c2 < 64 * 128; c2 += 256) {
      int r = c2 >> 7, kb = c2 & 127;
      const float* src = Wih1 + (long)(rbase + r) * HH + kb * 8;
      v8b w;
#pragma unroll
      for (int j = 0; j < 8; ++j) w[j] = (short)f2bf(src[j]);
      *(v8b*)&Wlds[(kb * 64 + r) * 8] = w;
    }
    __syncthreads();
    float bias[4];
#pragma unroll
    for (int nt = 0; nt < 4; ++nt) bias[nt] = b1[rbase + nt * 16 + m16];
    for (int t = 0; t < TT; ++t) {
      if (tid == 0) spin64(&cL0[t * CPAD]);
      else if (tid == 64 && t >= XP1_SLOTS) spin64(&cL1[(t - XP1_SLOTS) * CPAD]);
      __syncthreads();
      compiler_barrier();
      v4f a0 = {0,0,0,0}, a1 = {0,0,0,0}, a2 = {0,0,0,0}, a3 = {0,0,0,0};
      const u16* hp = h0r + (t & (H0_SLOTS - 1)) * (BB * HH) + bm * HH + q * 8;
      khloop(hp, q, m16, a0, a1, a2, a3);
      float* xpS = xp1 + (long)(t & (XP1_SLOTS - 1)) * (GG * BB);
      stg16_f(&xpS[(long)(rbase + 0 * 16 + m16) * BB + bq], a0 + bias[0]);
      stg16_f(&xpS[(long)(rbase + 1 * 16 + m16) * BB + bq], a1 + bias[1]);
      stg16_f(&xpS[(long)(rbase + 2 * 16 + m16) * BB + bq], a2 + bias[2]);
      stg16_f(&xpS[(long)(rbase + 3 * 16 + m16) * BB + bq], a3 + bias[3]);
      drain_stores();
      __syncthreads();
      bump(&cA1[t * CPAD]);
    }
  } else {
    // ===== L1: gates = xp1 + W_hh1 @ h1[t-1]; cell + last-step capture =====
    const int ubase = sid * 16;
    for (int c2 = tid; c2 < 64 * 128; c2 += 256) {
      int r = c2 >> 7, kb = c2 & 127;
      int grow = (r >> 4) * HH + ubase + (r & 15);
      const float* src = Whh1 + (long)grow * HH + kb * 8;
      v8b w;
#pragma unroll
      for (int j = 0; j < 8; ++j) w[j] = (short)f2bf(src[j]);
      *(v8b*)&Wlds[(kb * 64 + r) * 8] = w;
    }
    __syncthreads();
    float cst[4] = {0.f, 0.f, 0.f, 0.f};
    int cap[4];
#pragma unroll
    for (int r = 0; r < 4; ++r) {
      int l = lens[bq + r];
      cap[r] = (l > 0) ? (l - 1) : (TT - 1);
    }
    for (int t = 0; t < TT; ++t) {
      if (tid == 0) spin64(&cA1[t * CPAD]);
      else if (tid == 64 && t >= 1) spin64(&cL1[(t - 1) * CPAD]);
      __syncthreads();
      compiler_barrier();
      const float* xpS = xp1 + (long)(t & (XP1_SLOTS - 1)) * (GG * BB);
      v4f xq0 = ldf16a(&xpS[(long)(0 * HH + ubase + m16) * BB + bq]);
      v4f xq1 = ldf16a(&xpS[(long)(1 * HH + ubase + m16) * BB + bq]);
      v4f xq2 = ldf16a(&xpS[(long)(2 * HH + ubase + m16) * BB + bq]);
      v4f xq3 = ldf16a(&xpS[(long)(3 * HH + ubase + m16) * BB + bq]);
      v4f a0 = {0,0,0,0}, a1 = {0,0,0,0}, a2 = {0,0,0,0}, a3 = {0,0,0,0};
      const u16* hp = h1r + ((t + H1_SLOTS - 1) & (H1_SLOTS - 1)) * (BB * HH) + bm * HH + q * 8;
      khloop(hp, q, m16, a0, a1, a2, a3);
      a0 += xq0; a1 += xq1; a2 += xq2; a3 += xq3;
      u16* hw = h1r + (t & (H1_SLOTS - 1)) * (BB * HH);
#pragma unroll
      for (int r = 0; r < 4; ++r) {
        float cn = sigm(a1[r]) * cst[r] + sigm(a0[r]) * tanhf(a2[r]);
        cst[r] = cn;
        float hv = sigm(a3[r]) * tanhf(cn);
        stg2_h(&hw[(bq + r) * HH + ubase + m16], f2bf(hv));
        if (t == cap[r]) stg4_f(&lasth[(long)(bq + r) * HH + ubase + m16], hv);
      }
      drain_stores();
      __syncthreads();
      bump(&cL1[t * CPAD]);
    }
  }
}

// ---------------- final: out = last_h1 @ W_out^T + b_out (all fp32) ----------------
__global__ void out_kernel(const float* __restrict__ lasth, const float* __restrict__ Wout,
                           const float* __restrict__ bout, float* __restrict__ out) {
  int b = blockIdx.x;
  int k = threadIdx.x;
  if (k < 10) {
    float acc = bout[k];
    const float* hb = lasth + (long)b * HH;
    const float* wr = Wout + (long)k * HH;
    for (int j = 0; j < HH; ++j) acc += hb[j] * wr[j];
    out[b * 10 + k] = acc;
  }
}

extern "C" void kernel_launch(void* const* d_in, const int* in_sizes, int n_in,
                              void* d_out, int out_size, void* d_ws, size_t ws_size,
                              hipStream_t stream) {
  const int*   x    = (const int*)d_in[0];
  const float* emb  = (const float*)d_in[1];
  const float* Wih0 = (const float*)d_in[2];
  const float* Whh0 = (const float*)d_in[3];
  const float* b0   = (const float*)d_in[4];
  const float* Wih1 = (const float*)d_in[5];
  const float* Whh1 = (const float*)d_in[6];
  const float* b1   = (const float*)d_in[7];
  const float* Wout = (const float*)d_in[8];
  const float* bout = (const float*)d_in[9];

  char* ws = (char*)d_ws;
  u16*   e16   = (u16*)(ws + 0);            // 33,554,432 B
  float* xp0   = (float*)(ws + 33554432);   // 8 slots * 1 MB = 8,388,608 B
  float* xp1   = (float*)(ws + 41943040);   // 4 slots = 4,194,304 B
  u16*   h0r   = (u16*)(ws + 46137344);     // 8 slots * 128 KB = 1,048,576 B
  u16*   h1r   = (u16*)(ws + 47185920);     // 4 slots = 524,288 B
  float* lasth = (float*)(ws + 47710208);   // 262,144 B
  int*   lens  = (int*)(ws + 47972352);     // 256 B
  u32*   cnts  = (u32*)(ws + 47972608);     // 4 * 512 * 64 B = 131,072 B  (total ~48.1 MB)
  u32* cA0 = cnts;
  u32* cL0 = cA0 + TT * CPAD;
  u32* cA1 = cL0 + TT * CPAD;
  u32* cL1 = cA1 + TT * CPAD;
  int cnt_u32s = 4 * TT * CPAD;

  hipFuncSetAttribute((const void*)lstm_persist,
                      hipFuncAttributeMaxDynamicSharedMemorySize, 131072);

  prep_kernel<<<2048, 256, 0, stream>>>(x, emb, e16, h0r, h1r, lens, cnts, cnt_u32s);
  lstm_persist<<<4 * NSG, 256, 131072, stream>>>(e16, Wih0, Whh0, b0, Wih1, Whh1, b1, lens,
                                                 xp0, xp1, h0r, h1r, lasth, cA0, cL0, cA1, cL1);
  out_kernel<<<BB, 64, 0, stream>>>(lasth, Wout, bout, (float*)d_out);
}